// Round 14
// baseline (203.556 us; speedup 1.0000x reference)
//
#include <hip/hip_runtime.h>
#include <hip/hip_bf16.h>
#include <stdint.h>

typedef __attribute__((ext_vector_type(8))) short bf16x8;
typedef __attribute__((ext_vector_type(4))) float f32x4;
typedef __attribute__((ext_vector_type(16))) float f32x16;

typedef __attribute__((address_space(1))) const uint32_t gu32;
typedef __attribute__((address_space(3))) uint32_t lu32;

#define N_PIX 4096
#define C_CH  256
#define SCALE_LOG2E (0.0625f * 1.4426950408889634f)  // c^-0.5 * log2(e)

__device__ __forceinline__ unsigned short f2bf(float f) {
    unsigned int u = __float_as_uint(f);
    unsigned int r = (u + 0x7FFFu + ((u >> 16) & 1u)) >> 16;  // RNE
    return (unsigned short)r;
}
__device__ __forceinline__ float bf2f(short s) {
    return __uint_as_float(((unsigned int)(unsigned short)s) << 16);
}

// ---------------- kernel 1: groupnorm stats + weight cast ------------------
__global__ void prep_kernel(const float* __restrict__ x,
                            const float* __restrict__ gn_w,
                            const float* __restrict__ gn_b,
                            const float* __restrict__ qkv_w,
                            const float* __restrict__ out_w,
                            float* __restrict__ a_out,   // [4][256]
                            float* __restrict__ b_out,   // [4][256]
                            unsigned short* __restrict__ wq,   // [768][256]
                            unsigned short* __restrict__ w2) { // [256][256]
    int bid = blockIdx.x;
    if (bid >= 128) {
        int i = (bid - 128) * 256 + threadIdx.x;   // 0..196607
        wq[i] = f2bf(qkv_w[i]);
        if (i < 65536) w2[i] = f2bf(out_w[i]);
        return;
    }
    int b = bid >> 5, g = bid & 31;
    const float* base = x + ((size_t)(b * C_CH + g * 8)) * N_PIX;
    float s1 = 0.f, s2 = 0.f;
    for (int i = threadIdx.x; i < 8 * N_PIX; i += 256) {
        float v = base[i];
        s1 += v; s2 += v * v;
    }
    __shared__ float r1[256], r2[256];
    r1[threadIdx.x] = s1; r2[threadIdx.x] = s2;
    __syncthreads();
    for (int off = 128; off > 0; off >>= 1) {
        if (threadIdx.x < off) {
            r1[threadIdx.x] += r1[threadIdx.x + off];
            r2[threadIdx.x] += r2[threadIdx.x + off];
        }
        __syncthreads();
    }
    if (threadIdx.x < 8) {
        float mean = r1[0] * (1.f / 32768.f);
        float var  = r2[0] * (1.f / 32768.f) - mean * mean;
        float rstd = rsqrtf(var + 1e-5f);
        int c = g * 8 + threadIdx.x;
        float A = rstd * gn_w[c];
        a_out[b * C_CH + c] = A;
        b_out[b * C_CH + c] = gn_b[c] - mean * A;
    }
}

// ---------------- kernel 2: fused norm + QKV GEMM (wq staged in LDS) -------
__global__ __launch_bounds__(256)
void qkv_gemm_kernel(const float* __restrict__ x,
                     const float* __restrict__ a_arr,
                     const float* __restrict__ bb_arr,
                     const unsigned short* __restrict__ wq,
                     const float* __restrict__ qkv_b,
                     unsigned short* __restrict__ q_seq,
                     unsigned short* __restrict__ k_seq,
                     unsigned short* __restrict__ vT) {
    __shared__ char wlds[2][16384];   // [256 o-rows][32 c] bf16 per ks slice
    int pb   = blockIdx.x;          // 0..63
    int och  = blockIdx.y;          // 0..2
    int b    = blockIdx.z;          // 0..3
    int tid  = threadIdx.x;
    int wave = tid >> 6;
    int lane = tid & 63;
    int lo = lane & 15, hi = lane >> 4;
    int prow = pb * 64 + wave * 16 + lo;
    const float* xb = x + (size_t)b * C_CH * N_PIX;
    const float* av = a_arr + b * C_CH;
    const float* bv = bb_arr + b * C_CH;

    auto stageW = [&](int buf, int ks) {
#pragma unroll
        for (int pass = 0; pass < 4; pass++) {
            int chunk = pass * 256 + tid;        // 0..1023
            int r = chunk >> 2, cslot = chunk & 3;
            const char* src = (const char*)wq + (size_t)(och * 256 + r) * 512
                              + ks * 64 + cslot * 16;
            __builtin_amdgcn_global_load_lds((gu32*)src,
                                             (lu32*)(wlds[buf] + chunk * 16), 16, 0, 0);
        }
    };

    f32x4 acc[16];
#pragma unroll
    for (int t = 0; t < 16; t++) acc[t] = (f32x4)0.f;

    stageW(0, 0);
    __syncthreads();

#pragma unroll
    for (int ks = 0; ks < 8; ks++) {
        int buf = ks & 1;
        if (ks < 7) stageW(buf ^ 1, ks + 1);
        int c0 = ks * 32 + hi * 8;
        bf16x8 afrag;
#pragma unroll
        for (int i = 0; i < 8; i++) {
            float xv = xb[(size_t)(c0 + i) * N_PIX + prow];
            float v  = fmaf(av[c0 + i], xv, bv[c0 + i]);
            afrag[i] = (short)f2bf(v);
        }
#pragma unroll
        for (int t = 0; t < 16; t++) {
            bf16x8 bfrag = *(const bf16x8*)(wlds[buf] + (t * 16 + lo) * 64 + hi * 16);
            acc[t] = __builtin_amdgcn_mfma_f32_16x16x32_bf16(afrag, bfrag, acc[t], 0, 0, 0);
        }
        __syncthreads();
    }

    int p_base = pb * 64 + wave * 16 + hi * 4;
#pragma unroll
    for (int t = 0; t < 16; t++) {
        int o = och * 256 + t * 16 + lo;
        float bias = qkv_b[o];
        if (och == 2) {
            ushort4 pk;
            pk.x = f2bf(acc[t][0] + bias);
            pk.y = f2bf(acc[t][1] + bias);
            pk.z = f2bf(acc[t][2] + bias);
            pk.w = f2bf(acc[t][3] + bias);
            *(ushort4*)(vT + ((size_t)(b * C_CH + (o - 512))) * N_PIX + p_base) = pk;
        } else {
            float sc = (och == 0) ? SCALE_LOG2E : 1.f;
            unsigned short* dst = (och == 0 ? q_seq : k_seq) + (size_t)b * N_PIX * C_CH;
            int cc = o - och * 256;
#pragma unroll
            for (int r = 0; r < 4; r++)
                dst[(size_t)(p_base + r) * 256 + cc] = f2bf((acc[t][r] + bias) * sc);
        }
    }
}

// ---------------- kernel 3: flash attention partials -----------------------
// 512 blocks x 8 waves (512 thr), 2 blocks/CU (67.6KB LDS, 128 VGPR).
// Block = (b, kv-quarter, pq): 128 q x 1024 kv. Wave = (qg 0..3, kvh 0..1):
// q rows pq*128 + qg*32; kv slice kvh*32 of each 64-kv tile (16 tiles).
// K [64][512B] swz slot^(r&31); V 2ch/row [128][256B] swz slot^(row&15).
// Epilogue 3-phase: kvh0 dump strips -> kvh1 merge in place -> coalesced write.
__global__ __launch_bounds__(512, 2)
void attn_kernel(const unsigned short* __restrict__ q_seq,
                 const unsigned short* __restrict__ k_seq,
                 const unsigned short* __restrict__ vT,
                 unsigned short* __restrict__ o_part,   // [4][4][4096][256] bf16
                 float* __restrict__ m_part,            // [4][4][4096]
                 float* __restrict__ l_part) {          // [4][4][4096]
    extern __shared__ char lds[];
    char* Kt = lds;                      // 32KB
    char* Vt = lds + 32768;              // 32KB
    float* Ml = (float*)(lds + 65536);   // [8][32]
    float* Ll = (float*)(lds + 66560);   // [8][32]

    int bid  = blockIdx.x;
    int work = (bid & 7) * 64 + (bid >> 3);   // XCD-chunked (512 wgs)
    int group = work >> 5;          // 0..15
    int b   = group >> 2;
    int qtr = group & 3;
    int pq  = work & 31;
    int tid = threadIdx.x;
    int wave = tid >> 6, lane = tid & 63;
    int l31 = lane & 31, hi2 = lane >> 5;
    int qg = wave >> 1, kvh = wave & 1;
    int p0 = pq * 128 + qg * 32;
    int kvb = kvh * 32;

    const unsigned short* qb = q_seq + (size_t)b * N_PIX * C_CH;
    const unsigned short* kb = k_seq + (size_t)b * N_PIX * C_CH;
    const unsigned short* vb = vT    + (size_t)b * C_CH * N_PIX;

    bf16x8 qf[16];
#pragma unroll
    for (int cs = 0; cs < 16; cs++)
        qf[cs] = *(const bf16x8*)(qb + (size_t)(p0 + l31) * 256 + cs * 16 + hi2 * 8);

    f32x16 oacc[8];
#pragma unroll
    for (int t = 0; t < 8; t++) oacc[t] = (f32x16)0.f;
    float m = -1e30f, lsum = 0.f;

    int kswz = l31 << 4;

    for (int t = 0; t < 16; t++) {
        if (t) __syncthreads();
        int j0 = qtr * 1024 + t * 64;
        const char* kjb = (const char*)kb + (size_t)j0 * 512;
        const char* vjb = (const char*)vb + (size_t)j0 * 2;
#pragma unroll
        for (int p = 0; p < 4; p++) {
            int kr = p * 16 + (tid >> 5);        // 0..63
            int ks = tid & 31;
            __builtin_amdgcn_global_load_lds(
                (gu32*)(kjb + kr * 512 + ((ks ^ (kr & 31)) << 4)),
                (lu32*)(Kt + p * 8192 + tid * 16), 16, 0, 0);
            int vr = p * 32 + (tid >> 4);        // 0..127
            int vs = tid & 15;
            int tt = vs ^ (vr & 15);
            int c  = 2 * vr + (tt >> 3);
            __builtin_amdgcn_global_load_lds(
                (gu32*)(vjb + (size_t)c * 8192 + ((tt & 7) << 4)),
                (lu32*)(Vt + p * 8192 + tid * 16), 16, 0, 0);
        }
        __syncthreads();

        // ---- QK^T (swapped): D[kv][q] ----
        f32x16 sacc = (f32x16)0.f;
#pragma unroll
        for (int cs = 0; cs < 16; cs++) {
            bf16x8 kf = *(const bf16x8*)(Kt + (kvb + l31) * 512 + ((cs * 32 + hi2 * 16) ^ kswz));
            sacc = __builtin_amdgcn_mfma_f32_32x32x16_bf16(kf, qf[cs], sacc, 0, 0, 0);
        }

        // ---- per-lane online softmax (lane l31 = q, regs = 16 kv) ----
        float mx = sacc[0];
#pragma unroll
        for (int r = 1; r < 16; r++) mx = fmaxf(mx, sacc[r]);
        mx = fmaxf(mx, __shfl_xor(mx, 32, 64));
        if (__any(mx > m + 8.f)) {          // defer-max (T13)
            float mC = fmaxf(m, mx);
            float al = __builtin_amdgcn_exp2f(m - mC);
            m = mC; lsum *= al;
#pragma unroll
            for (int r = 0; r < 16; r++) {
                int qr = (r & 3) + 8 * (r >> 2) + 4 * hi2;
                float ar = __shfl(al, qr, 64);
#pragma unroll
                for (int ct = 0; ct < 8; ct++) oacc[ct][r] *= ar;
            }
        }
        f32x16 pexp;
        float psum = 0.f;
#pragma unroll
        for (int r = 0; r < 16; r++) {
            float pe = __builtin_amdgcn_exp2f(sacc[r] - m);
            pexp[r] = pe; psum += pe;
        }
        psum += __shfl_xor(psum, 32, 64);
        lsum += psum;

        // ---- pack P (cvt_pk + permlane32_swap, T12; d=LOW, s=HIGH) ----
        bf16x8 pa0, pa1;
        {
            unsigned int x0, x1, y0, y1;
            asm("v_cvt_pk_bf16_f32 %0, %1, %2" : "=v"(x0) : "v"(pexp[0]), "v"(pexp[1]));
            asm("v_cvt_pk_bf16_f32 %0, %1, %2" : "=v"(x1) : "v"(pexp[2]), "v"(pexp[3]));
            asm("v_cvt_pk_bf16_f32 %0, %1, %2" : "=v"(y0) : "v"(pexp[4]), "v"(pexp[5]));
            asm("v_cvt_pk_bf16_f32 %0, %1, %2" : "=v"(y1) : "v"(pexp[6]), "v"(pexp[7]));
            asm("v_permlane32_swap_b32 %0, %1" : "+v"(x0), "+v"(y0));
            asm("v_permlane32_swap_b32 %0, %1" : "+v"(x1), "+v"(y1));
            union { unsigned int u[4]; bf16x8 v; } f0;
            f0.u[0] = x0; f0.u[1] = x1; f0.u[2] = y0; f0.u[3] = y1;
            pa0 = f0.v;
            asm("v_cvt_pk_bf16_f32 %0, %1, %2" : "=v"(x0) : "v"(pexp[8]), "v"(pexp[9]));
            asm("v_cvt_pk_bf16_f32 %0, %1, %2" : "=v"(x1) : "v"(pexp[10]), "v"(pexp[11]));
            asm("v_cvt_pk_bf16_f32 %0, %1, %2" : "=v"(y0) : "v"(pexp[12]), "v"(pexp[13]));
            asm("v_cvt_pk_bf16_f32 %0, %1, %2" : "=v"(y1) : "v"(pexp[14]), "v"(pexp[15]));
            asm("v_permlane32_swap_b32 %0, %1" : "+v"(x0), "+v"(y0));
            asm("v_permlane32_swap_b32 %0, %1" : "+v"(x1), "+v"(y1));
            union { unsigned int u[4]; bf16x8 v; } f1;
            f1.u[0] = x0; f1.u[1] = x1; f1.u[2] = y0; f1.u[3] = y1;
            pa1 = f1.v;
        }

        // ---- PV: D[q][c] += P(32q x 32kv) * V(kv x 32c) ----
#pragma unroll
        for (int ct = 0; ct < 8; ct++) {
            int c = ct * 32 + l31;
            int vrow = c >> 1;
            int s0i = (c & 1) * 8 + kvh * 4 + hi2;
            bf16x8 vf0 = *(const bf16x8*)(Vt + vrow * 256 + ((s0i ^ (vrow & 15)) << 4));
            oacc[ct] = __builtin_amdgcn_mfma_f32_32x32x16_bf16(pa0, vf0, oacc[ct], 0, 0, 0);
            int s1i = s0i + 2;
            bf16x8 vf1 = *(const bf16x8*)(Vt + vrow * 256 + ((s1i ^ (vrow & 15)) << 4));
            oacc[ct] = __builtin_amdgcn_mfma_f32_32x32x16_bf16(pa1, vf1, oacc[ct], 0, 0, 0);
        }
    }
    __syncthreads();   // all compute done -> strips may overlay K/V

    // ---- epilogue phase 1: stats + kvh==0 dump strips ----
    if (lane < 32) { Ml[wave * 32 + lane] = m; Ll[wave * 32 + lane] = lsum; }
    if (kvh == 0) {
        char* Ow = lds + qg * 16384;   // [32 q][512B], swz q<<4
#pragma unroll
        for (int ct = 0; ct < 8; ct++)
#pragma unroll
            for (int r = 0; r < 16; r++) {
                int q = (r & 3) + 8 * (r >> 2) + 4 * hi2;
                int cb = (ct * 32 + l31) * 2;
                *(unsigned short*)(Ow + q * 512 + (cb ^ (q << 4))) = f2bf(oacc[ct][r]);
            }
    }
    __syncthreads();
    size_t pbase = (size_t)(qtr * 4 + b) * N_PIX;
    // ---- phase 2: kvh==1 merges into strip ----
    if (kvh == 1) {
        char* Ow = lds + qg * 16384;
        float mp = Ml[(wave - 1) * 32 + l31], lp = Ll[(wave - 1) * 32 + l31];
        float mn = fmaxf(m, mp);
        float fo = __builtin_amdgcn_exp2f(m - mn);
        float fp = __builtin_amdgcn_exp2f(mp - mn);
        float lm = lsum * fo + lp * fp;
        if (lane < 32) {
            m_part[pbase + p0 + l31] = mn;
            l_part[pbase + p0 + l31] = lm;
        }
        float FO[16], FP[16];
#pragma unroll
        for (int r = 0; r < 16; r++) {
            int qr = (r & 3) + 8 * (r >> 2) + 4 * hi2;
            FO[r] = __shfl(fo, qr, 64);
            FP[r] = __shfl(fp, qr, 64);
        }
#pragma unroll
        for (int ct = 0; ct < 8; ct++)
#pragma unroll
            for (int r = 0; r < 16; r++) {
                int q = (r & 3) + 8 * (r >> 2) + 4 * hi2;
                int cb = (ct * 32 + l31) * 2;
                unsigned short* ad = (unsigned short*)(Ow + q * 512 + (cb ^ (q << 4)));
                float mg = bf2f((short)*ad) * FP[r] + oacc[ct][r] * FO[r];
                *ad = f2bf(mg);
            }
    }
    __syncthreads();
    // ---- phase 3: coalesced write of 128 rows x 256 c bf16 ----
    {
        int ql = tid >> 2;               // 0..127
        int qr = ql & 31, qg2 = ql >> 5;
        unsigned short* orow = o_part + (pbase + pq * 128 + ql) * C_CH;
#pragma unroll
        for (int i = 0; i < 8; i++) {
            int s = i * 4 + (tid & 3);           // 16B slot 0..31
            int cb = (s * 16) ^ (qr << 4);
            bf16x8 v = *(const bf16x8*)(lds + (size_t)qg2 * 16384 + qr * 512 + cb);
            *(bf16x8*)(orow + s * 8) = v;
        }
    }
}

// ---------------- kernel 4: 4-way combine + out-proj + residual ------------
// 512 blocks x 256 thr (4 waves = 2 row-groups x 2 o-halves).
__global__ __launch_bounds__(256)
void combine_kernel(const unsigned short* __restrict__ o_part,
                    const float* __restrict__ m_part,
                    const float* __restrict__ l_part,
                    const unsigned short* __restrict__ w2,
                    const float* __restrict__ out_b,
                    const float* __restrict__ x,
                    float* __restrict__ y) {
    int bid = blockIdx.x;
    int b = bid >> 7, pr = bid & 127;
    int tid = threadIdx.x;
    int wave = tid >> 6, lane = tid & 63;
    int lo = lane & 15, hi = lane >> 4;
    int rowgrp = wave & 1, ohalf = wave >> 1;
    int p0 = pr * 32 + rowgrp * 16;
    int row = p0 + lo;
    size_t idx[4];
    float mk[4], lk[4];
    float mm = -1e30f;
#pragma unroll
    for (int k = 0; k < 4; k++) {
        idx[k] = (size_t)(k * 4 + b) * N_PIX + row;
        mk[k] = m_part[idx[k]]; lk[k] = l_part[idx[k]];
        mm = fmaxf(mm, mk[k]);
    }
    float fsum = 0.f, fk[4];
#pragma unroll
    for (int k = 0; k < 4; k++) {
        fk[k] = __builtin_amdgcn_exp2f(mk[k] - mm);
        fsum += fk[k] * lk[k];
    }
    float rl = 1.f / fsum;
#pragma unroll
    for (int k = 0; k < 4; k++) fk[k] *= rl;

    f32x4 acc2[8];
#pragma unroll
    for (int t = 0; t < 8; t++) acc2[t] = (f32x4)0.f;

#pragma unroll
    for (int ks = 0; ks < 8; ks++) {
        int c0 = ks * 32 + hi * 8;
        bf16x8 a0 = *(const bf16x8*)(o_part + idx[0] * C_CH + c0);
        bf16x8 a1 = *(const bf16x8*)(o_part + idx[1] * C_CH + c0);
        bf16x8 a2 = *(const bf16x8*)(o_part + idx[2] * C_CH + c0);
        bf16x8 a3 = *(const bf16x8*)(o_part + idx[3] * C_CH + c0);
        bf16x8 of;
#pragma unroll
        for (int i = 0; i < 8; i++)
            of[i] = (short)f2bf(fk[0] * bf2f(a0[i]) + fk[1] * bf2f(a1[i]) +
                                fk[2] * bf2f(a2[i]) + fk[3] * bf2f(a3[i]));
#pragma unroll
        for (int ot = 0; ot < 8; ot++) {
            int o = ohalf * 128 + ot * 16 + lo;
            bf16x8 wf = *(const bf16x8*)(w2 + (size_t)o * 256 + c0);
            acc2[ot] = __builtin_amdgcn_mfma_f32_16x16x32_bf16(of, wf, acc2[ot], 0, 0, 0);
        }
    }

    int p_base = p0 + hi * 4;
#pragma unroll
    for (int ot = 0; ot < 8; ot++) {
        int o = ohalf * 128 + ot * 16 + lo;
        float bias = out_b[o];
        size_t off = ((size_t)(b * C_CH + o)) * N_PIX + p_base;
        f32x4 xv = *(const f32x4*)(x + off);
        f32x4 outv;
#pragma unroll
        for (int r = 0; r < 4; r++) outv[r] = acc2[ot][r] + bias + xv[r];
        *(f32x4*)(y + off) = outv;
    }
}

// ---------------- launch ---------------------------------------------------
extern "C" void kernel_launch(void* const* d_in, const int* in_sizes, int n_in,
                              void* d_out, int out_size, void* d_ws, size_t ws_size,
                              hipStream_t stream) {
    const float* x     = (const float*)d_in[0];
    const float* gn_w  = (const float*)d_in[1];
    const float* gn_b  = (const float*)d_in[2];
    const float* qkv_w = (const float*)d_in[3];
    const float* qkv_b = (const float*)d_in[4];
    const float* out_w = (const float*)d_in[5];
    const float* out_b = (const float*)d_in[6];
    float* y = (float*)d_out;
    char* ws = (char*)d_ws;

    float* a_arr  = (float*)(ws);
    float* bb_arr = (float*)(ws + 4096);
    unsigned short* wq     = (unsigned short*)(ws + 8192);      // 384KB
    unsigned short* w2     = (unsigned short*)(ws + 401408);    // 128KB
    unsigned short* q_seq  = (unsigned short*)(ws + 532480);    // 8MB
    unsigned short* k_seq  = (unsigned short*)(ws + 532480 + 8388608);
    unsigned short* vT     = (unsigned short*)(ws + 532480 + 2 * 8388608);
    unsigned short* o_part = (unsigned short*)(ws + 532480 + 3 * 8388608);  // 32MB
    float* m_part = (float*)(ws + 59252736);   // 256KB
    float* l_part = (float*)(ws + 59514880);   // 256KB

    (void)hipFuncSetAttribute((const void*)attn_kernel,
                              hipFuncAttributeMaxDynamicSharedMemorySize, 67584);

    prep_kernel<<<896, 256, 0, stream>>>(x, gn_w, gn_b, qkv_w, out_w,
                                         a_arr, bb_arr, wq, w2);
    qkv_gemm_kernel<<<dim3(64, 3, 4), 256, 0, stream>>>(x, a_arr, bb_arr, wq, qkv_b,
                                                        q_seq, k_seq, vT);
    attn_kernel<<<512, 512, 67584, stream>>>(q_seq, k_seq, vT, o_part, m_part, l_part);
    combine_kernel<<<512, 256, 0, stream>>>(o_part, m_part, l_part, w2, out_b, x, y);
}

// Round 15
// 172.982 us; speedup vs baseline: 1.1767x; 1.1767x over previous
//
#include <hip/hip_runtime.h>
#include <hip/hip_bf16.h>
#include <stdint.h>

typedef __attribute__((ext_vector_type(8))) short bf16x8;
typedef __attribute__((ext_vector_type(4))) float f32x4;
typedef __attribute__((ext_vector_type(16))) float f32x16;

typedef __attribute__((address_space(1))) const uint32_t gu32;
typedef __attribute__((address_space(3))) uint32_t lu32;

#define N_PIX 4096
#define C_CH  256
#define KVB   128
#define SCALE_LOG2E (0.0625f * 1.4426950408889634f)  // c^-0.5 * log2(e)

__device__ __forceinline__ unsigned short f2bf(float f) {
    unsigned int u = __float_as_uint(f);
    unsigned int r = (u + 0x7FFFu + ((u >> 16) & 1u)) >> 16;  // RNE
    return (unsigned short)r;
}
__device__ __forceinline__ float bf2f(short s) {
    return __uint_as_float(((unsigned int)(unsigned short)s) << 16);
}

// ---------------- kernel 1: groupnorm stats + weight cast ------------------
__global__ void prep_kernel(const float* __restrict__ x,
                            const float* __restrict__ gn_w,
                            const float* __restrict__ gn_b,
                            const float* __restrict__ qkv_w,
                            const float* __restrict__ out_w,
                            float* __restrict__ a_out,   // [4][256]
                            float* __restrict__ b_out,   // [4][256]
                            unsigned short* __restrict__ wq,   // [768][256]
                            unsigned short* __restrict__ w2) { // [256][256]
    int bid = blockIdx.x;
    if (bid >= 128) {
        int i = (bid - 128) * 256 + threadIdx.x;   // 0..196607
        wq[i] = f2bf(qkv_w[i]);
        if (i < 65536) w2[i] = f2bf(out_w[i]);
        return;
    }
    int b = bid >> 5, g = bid & 31;
    const float* base = x + ((size_t)(b * C_CH + g * 8)) * N_PIX;
    float s1 = 0.f, s2 = 0.f;
    for (int i = threadIdx.x; i < 8 * N_PIX; i += 256) {
        float v = base[i];
        s1 += v; s2 += v * v;
    }
    __shared__ float r1[256], r2[256];
    r1[threadIdx.x] = s1; r2[threadIdx.x] = s2;
    __syncthreads();
    for (int off = 128; off > 0; off >>= 1) {
        if (threadIdx.x < off) {
            r1[threadIdx.x] += r1[threadIdx.x + off];
            r2[threadIdx.x] += r2[threadIdx.x + off];
        }
        __syncthreads();
    }
    if (threadIdx.x < 8) {
        float mean = r1[0] * (1.f / 32768.f);
        float var  = r2[0] * (1.f / 32768.f) - mean * mean;
        float rstd = rsqrtf(var + 1e-5f);
        int c = g * 8 + threadIdx.x;
        float A = rstd * gn_w[c];
        a_out[b * C_CH + c] = A;
        b_out[b * C_CH + c] = gn_b[c] - mean * A;
    }
}

// ---------------- kernel 2: fused norm + QKV GEMM (wq staged in LDS) -------
__global__ __launch_bounds__(256)
void qkv_gemm_kernel(const float* __restrict__ x,
                     const float* __restrict__ a_arr,
                     const float* __restrict__ bb_arr,
                     const unsigned short* __restrict__ wq,
                     const float* __restrict__ qkv_b,
                     unsigned short* __restrict__ q_seq,
                     unsigned short* __restrict__ k_seq,
                     unsigned short* __restrict__ vT) {
    __shared__ char wlds[2][16384];   // [256 o-rows][32 c] bf16 per ks slice
    int pb   = blockIdx.x;          // 0..63
    int och  = blockIdx.y;          // 0..2
    int b    = blockIdx.z;          // 0..3
    int tid  = threadIdx.x;
    int wave = tid >> 6;
    int lane = tid & 63;
    int lo = lane & 15, hi = lane >> 4;
    int prow = pb * 64 + wave * 16 + lo;
    const float* xb = x + (size_t)b * C_CH * N_PIX;
    const float* av = a_arr + b * C_CH;
    const float* bv = bb_arr + b * C_CH;

    auto stageW = [&](int buf, int ks) {
#pragma unroll
        for (int pass = 0; pass < 4; pass++) {
            int chunk = pass * 256 + tid;        // 0..1023
            int r = chunk >> 2, cslot = chunk & 3;
            const char* src = (const char*)wq + (size_t)(och * 256 + r) * 512
                              + ks * 64 + cslot * 16;
            __builtin_amdgcn_global_load_lds((gu32*)src,
                                             (lu32*)(wlds[buf] + chunk * 16), 16, 0, 0);
        }
    };

    f32x4 acc[16];
#pragma unroll
    for (int t = 0; t < 16; t++) acc[t] = (f32x4)0.f;

    stageW(0, 0);
    __syncthreads();

#pragma unroll
    for (int ks = 0; ks < 8; ks++) {
        int buf = ks & 1;
        if (ks < 7) stageW(buf ^ 1, ks + 1);
        int c0 = ks * 32 + hi * 8;
        bf16x8 afrag;
#pragma unroll
        for (int i = 0; i < 8; i++) {
            float xv = xb[(size_t)(c0 + i) * N_PIX + prow];
            float v  = fmaf(av[c0 + i], xv, bv[c0 + i]);
            afrag[i] = (short)f2bf(v);
        }
#pragma unroll
        for (int t = 0; t < 16; t++) {
            bf16x8 bfrag = *(const bf16x8*)(wlds[buf] + (t * 16 + lo) * 64 + hi * 16);
            acc[t] = __builtin_amdgcn_mfma_f32_16x16x32_bf16(afrag, bfrag, acc[t], 0, 0, 0);
        }
        __syncthreads();
    }

    int p_base = pb * 64 + wave * 16 + hi * 4;
#pragma unroll
    for (int t = 0; t < 16; t++) {
        int o = och * 256 + t * 16 + lo;
        float bias = qkv_b[o];
        if (och == 2) {
            ushort4 pk;
            pk.x = f2bf(acc[t][0] + bias);
            pk.y = f2bf(acc[t][1] + bias);
            pk.z = f2bf(acc[t][2] + bias);
            pk.w = f2bf(acc[t][3] + bias);
            *(ushort4*)(vT + ((size_t)(b * C_CH + (o - 512))) * N_PIX + p_base) = pk;
        } else {
            float sc = (och == 0) ? SCALE_LOG2E : 1.f;
            unsigned short* dst = (och == 0 ? q_seq : k_seq) + (size_t)b * N_PIX * C_CH;
            int cc = o - och * 256;
#pragma unroll
            for (int r = 0; r < 4; r++)
                dst[(size_t)(p_base + r) * 256 + cc] = f2bf((acc[t][r] + bias) * sc);
        }
    }
}

// ---------------- kernel 3: flash attention partials (R8/R13 structure) ----
// 256 blocks x 8 waves (512 thr). Block = (b, kv-half, pq): 128 q x 2048 kv.
// Wave = (qg 0..3, kvh 0..1); per 128-kv tile: two 32-kv sub-iterations.
// Single-buffered K(64KB)+V(64KB) via global_load_lds, 16 tiles.
// T5: setprio(1) around MFMA clusters.
__global__ __launch_bounds__(512, 2)
void attn_kernel(const unsigned short* __restrict__ q_seq,
                 const unsigned short* __restrict__ k_seq,
                 const unsigned short* __restrict__ vT,
                 unsigned short* __restrict__ o_part,   // [2][4][4096][256] bf16
                 float* __restrict__ m_part,            // [2][4][4096]
                 float* __restrict__ l_part) {          // [2][4][4096]
    extern __shared__ char lds[];
    char* Kt = lds;                      // [128 kv][512B], swz (row&31)<<4
    char* Vt = lds + 65536;              // [256 c][256B], swz (slot^(c&15))
    float* Ml = (float*)(lds + 131072);  // [8][32]
    float* Ll = (float*)(lds + 132096);  // [8][32]

    int bid  = blockIdx.x;
    int work = (bid & 7) * 32 + (bid >> 3);   // XCD-chunked
    int group = work >> 5;          // 0..7
    int b    = group >> 1;
    int half = group & 1;
    int pq   = work & 31;
    int tid = threadIdx.x;
    int wave = tid >> 6, lane = tid & 63;
    int l31 = lane & 31, hi2 = lane >> 5;
    int qg = wave >> 1, kvh = wave & 1;
    int p0 = pq * 128 + qg * 32;

    const unsigned short* qb = q_seq + (size_t)b * N_PIX * C_CH;
    const unsigned short* kb = k_seq + (size_t)b * N_PIX * C_CH;
    const unsigned short* vb = vT    + (size_t)b * C_CH * N_PIX;

    int ktrow = tid >> 5, kcol = tid & 31;   // K row = p*16 + ktrow
    int vtrow = tid >> 4, vcol = tid & 15;   // V row = p*32 + vtrow

    bf16x8 qf[16];
#pragma unroll
    for (int cs = 0; cs < 16; cs++)
        qf[cs] = *(const bf16x8*)(qb + (size_t)(p0 + l31) * 256 + cs * 16 + hi2 * 8);

    f32x16 oacc[8];
#pragma unroll
    for (int t = 0; t < 8; t++) oacc[t] = (f32x16)0.f;
    float m = -1e30f, lsum = 0.f;

    int kswz = l31 << 4;
    int vswz = (l31 & 15) << 4;

    for (int t = 0; t < 16; t++) {
        if (t) __syncthreads();
        int j0 = half * 2048 + t * KVB;
#pragma unroll
        for (int p = 0; p < 8; p++) {
            int kr = p * 16 + ktrow;
            const char* ksrc = (const char*)(kb + (size_t)(j0 + kr) * 256)
                               + ((kcol ^ (kr & 31)) << 4);
            __builtin_amdgcn_global_load_lds((gu32*)ksrc, (lu32*)(Kt + p * 8192 + tid * 16), 16, 0, 0);
            int vr = p * 32 + vtrow;
            const char* vsrc = (const char*)(vb + (size_t)vr * N_PIX + j0)
                               + ((vcol ^ (vr & 15)) << 4);
            __builtin_amdgcn_global_load_lds((gu32*)vsrc, (lu32*)(Vt + p * 8192 + tid * 16), 16, 0, 0);
        }
        __syncthreads();

#pragma unroll
        for (int sub = 0; sub < 2; sub++) {
            int kvb = kvh * 64 + sub * 32;

            f32x16 sacc = (f32x16)0.f;
            __builtin_amdgcn_s_setprio(1);
#pragma unroll
            for (int cs = 0; cs < 16; cs++) {
                bf16x8 kf = *(const bf16x8*)(Kt + (kvb + l31) * 512 + ((cs * 32 + hi2 * 16) ^ kswz));
                sacc = __builtin_amdgcn_mfma_f32_32x32x16_bf16(kf, qf[cs], sacc, 0, 0, 0);
            }
            __builtin_amdgcn_s_setprio(0);

            float mx = sacc[0];
#pragma unroll
            for (int r = 1; r < 16; r++) mx = fmaxf(mx, sacc[r]);
            mx = fmaxf(mx, __shfl_xor(mx, 32, 64));
            if (__any(mx > m + 8.f)) {          // defer-max (T13)
                float mC = fmaxf(m, mx);
                float al = __builtin_amdgcn_exp2f(m - mC);
                m = mC; lsum *= al;
#pragma unroll
                for (int r = 0; r < 16; r++) {
                    int qr = (r & 3) + 8 * (r >> 2) + 4 * hi2;
                    float ar = __shfl(al, qr, 64);
#pragma unroll
                    for (int ct = 0; ct < 8; ct++) oacc[ct][r] *= ar;
                }
            }
            f32x16 pexp;
            float psum = 0.f;
#pragma unroll
            for (int r = 0; r < 16; r++) {
                float pe = __builtin_amdgcn_exp2f(sacc[r] - m);
                pexp[r] = pe; psum += pe;
            }
            psum += __shfl_xor(psum, 32, 64);
            lsum += psum;

            bf16x8 pa0, pa1;
            {
                unsigned int x0, x1, y0, y1;
                asm("v_cvt_pk_bf16_f32 %0, %1, %2" : "=v"(x0) : "v"(pexp[0]), "v"(pexp[1]));
                asm("v_cvt_pk_bf16_f32 %0, %1, %2" : "=v"(x1) : "v"(pexp[2]), "v"(pexp[3]));
                asm("v_cvt_pk_bf16_f32 %0, %1, %2" : "=v"(y0) : "v"(pexp[4]), "v"(pexp[5]));
                asm("v_cvt_pk_bf16_f32 %0, %1, %2" : "=v"(y1) : "v"(pexp[6]), "v"(pexp[7]));
                asm("v_permlane32_swap_b32 %0, %1" : "+v"(x0), "+v"(y0));
                asm("v_permlane32_swap_b32 %0, %1" : "+v"(x1), "+v"(y1));
                union { unsigned int u[4]; bf16x8 v; } f0;
                f0.u[0] = x0; f0.u[1] = x1; f0.u[2] = y0; f0.u[3] = y1;
                pa0 = f0.v;
                asm("v_cvt_pk_bf16_f32 %0, %1, %2" : "=v"(x0) : "v"(pexp[8]), "v"(pexp[9]));
                asm("v_cvt_pk_bf16_f32 %0, %1, %2" : "=v"(x1) : "v"(pexp[10]), "v"(pexp[11]));
                asm("v_cvt_pk_bf16_f32 %0, %1, %2" : "=v"(y0) : "v"(pexp[12]), "v"(pexp[13]));
                asm("v_cvt_pk_bf16_f32 %0, %1, %2" : "=v"(y1) : "v"(pexp[14]), "v"(pexp[15]));
                asm("v_permlane32_swap_b32 %0, %1" : "+v"(x0), "+v"(y0));
                asm("v_permlane32_swap_b32 %0, %1" : "+v"(x1), "+v"(y1));
                union { unsigned int u[4]; bf16x8 v; } f1;
                f1.u[0] = x0; f1.u[1] = x1; f1.u[2] = y0; f1.u[3] = y1;
                pa1 = f1.v;
            }

            __builtin_amdgcn_s_setprio(1);
#pragma unroll
            for (int ct = 0; ct < 8; ct++) {
                int c = ct * 32 + l31;
                bf16x8 vf0 = *(const bf16x8*)(Vt + c * 256 + ((kvb * 2 + hi2 * 16) ^ vswz));
                oacc[ct] = __builtin_amdgcn_mfma_f32_32x32x16_bf16(pa0, vf0, oacc[ct], 0, 0, 0);
                bf16x8 vf1 = *(const bf16x8*)(Vt + c * 256 + ((kvb * 2 + 32 + hi2 * 16) ^ vswz));
                oacc[ct] = __builtin_amdgcn_mfma_f32_32x32x16_bf16(pa1, vf1, oacc[ct], 0, 0, 0);
            }
            __builtin_amdgcn_s_setprio(0);
        }
    }
    __syncthreads();

    // ---- epilogue: raw O~ + (m,l) to LDS, 2-way kvh merge, write partials --
    char* Ow = lds + wave * 16384;   // [32 q][512B], swz (q&31)<<4
#pragma unroll
    for (int ct = 0; ct < 8; ct++) {
#pragma unroll
        for (int r = 0; r < 16; r++) {
            int q = (r & 3) + 8 * (r >> 2) + 4 * hi2;
            int cb = (ct * 32 + l31) * 2;
            *(unsigned short*)(Ow + q * 512 + (cb ^ (q << 4))) = f2bf(oacc[ct][r]);
        }
    }
    if (lane < 32) { Ml[wave * 32 + lane] = m; Ll[wave * 32 + lane] = lsum; }
    __syncthreads();

    int ql = tid >> 2;               // 0..127
    int qr = ql & 31, qg2 = ql >> 5;
    float g[2];
    float m0 = Ml[(qg2 * 2 + 0) * 32 + qr];
    float m1 = Ml[(qg2 * 2 + 1) * 32 + qr];
    float mm = fmaxf(m0, m1);
    g[0] = __builtin_amdgcn_exp2f(m0 - mm);
    g[1] = __builtin_amdgcn_exp2f(m1 - mm);
    float ls = g[0] * Ll[(qg2 * 2 + 0) * 32 + qr] + g[1] * Ll[(qg2 * 2 + 1) * 32 + qr];
    int qglob = pq * 128 + ql;
    size_t pbase = (size_t)(half * 4 + b) * N_PIX;
    if ((tid & 3) == 0) {
        m_part[pbase + qglob] = mm;
        l_part[pbase + qglob] = ls;
    }
    unsigned short* orow = o_part + (pbase + qglob) * C_CH;
#pragma unroll
    for (int i = 0; i < 8; i++) {
        int s = i * 4 + (tid & 3);           // 16B slot 0..31
        int cb = (s * 16) ^ (qr << 4);
        bf16x8 a0 = *(const bf16x8*)(lds + (size_t)(qg2 * 2 + 0) * 16384 + qr * 512 + cb);
        bf16x8 a1 = *(const bf16x8*)(lds + (size_t)(qg2 * 2 + 1) * 16384 + qr * 512 + cb);
        union { unsigned short u[8]; bf16x8 v; } pk;
#pragma unroll
        for (int j = 0; j < 8; j++)
            pk.u[j] = f2bf(g[0] * bf2f(a0[j]) + g[1] * bf2f(a1[j]));
        *(bf16x8*)(orow + s * 8) = pk.v;
    }
}

// ---------------- kernel 4: combine halves + out-proj + residual -----------
// 512 blocks x 256 thr (4 waves = 2 row-groups x 2 o-halves).
__global__ __launch_bounds__(256)
void combine_kernel(const unsigned short* __restrict__ o_part,
                    const float* __restrict__ m_part,
                    const float* __restrict__ l_part,
                    const unsigned short* __restrict__ w2,
                    const float* __restrict__ out_b,
                    const float* __restrict__ x,
                    float* __restrict__ y) {
    int bid = blockIdx.x;
    int b = bid >> 7, pr = bid & 127;
    int tid = threadIdx.x;
    int wave = tid >> 6, lane = tid & 63;
    int lo = lane & 15, hi = lane >> 4;
    int rowgrp = wave & 1, ohalf = wave >> 1;
    int p0 = pr * 32 + rowgrp * 16;
    int row = p0 + lo;
    size_t i0 = (size_t)b * N_PIX + row;
    size_t i1 = (size_t)(4 + b) * N_PIX + row;
    float m0 = m_part[i0], l0 = l_part[i0];
    float m1 = m_part[i1], l1 = l_part[i1];
    float mm = fmaxf(m0, m1);
    float e0 = __builtin_amdgcn_exp2f(m0 - mm), e1 = __builtin_amdgcn_exp2f(m1 - mm);
    float rl = 1.f / (l0 * e0 + l1 * e1);
    float f0 = e0 * rl, f1 = e1 * rl;
    const unsigned short* P0 = o_part + i0 * C_CH;
    const unsigned short* P1 = o_part + i1 * C_CH;

    f32x4 acc2[8];
#pragma unroll
    for (int t = 0; t < 8; t++) acc2[t] = (f32x4)0.f;

#pragma unroll
    for (int ks = 0; ks < 8; ks++) {
        int c0 = ks * 32 + hi * 8;
        bf16x8 a0 = *(const bf16x8*)(P0 + c0);
        bf16x8 a1 = *(const bf16x8*)(P1 + c0);
        bf16x8 of;
#pragma unroll
        for (int i = 0; i < 8; i++)
            of[i] = (short)f2bf(bf2f(a0[i]) * f0 + bf2f(a1[i]) * f1);
#pragma unroll
        for (int ot = 0; ot < 8; ot++) {
            int o = ohalf * 128 + ot * 16 + lo;
            bf16x8 wf = *(const bf16x8*)(w2 + (size_t)o * 256 + c0);
            acc2[ot] = __builtin_amdgcn_mfma_f32_16x16x32_bf16(of, wf, acc2[ot], 0, 0, 0);
        }
    }

    int p_base = p0 + hi * 4;
#pragma unroll
    for (int ot = 0; ot < 8; ot++) {
        int o = ohalf * 128 + ot * 16 + lo;
        float bias = out_b[o];
        size_t off = ((size_t)(b * C_CH + o)) * N_PIX + p_base;
        f32x4 xv = *(const f32x4*)(x + off);
        f32x4 outv;
#pragma unroll
        for (int r = 0; r < 4; r++) outv[r] = acc2[ot][r] + bias + xv[r];
        *(f32x4*)(y + off) = outv;
    }
}

// ---------------- launch ---------------------------------------------------
extern "C" void kernel_launch(void* const* d_in, const int* in_sizes, int n_in,
                              void* d_out, int out_size, void* d_ws, size_t ws_size,
                              hipStream_t stream) {
    const float* x     = (const float*)d_in[0];
    const float* gn_w  = (const float*)d_in[1];
    const float* gn_b  = (const float*)d_in[2];
    const float* qkv_w = (const float*)d_in[3];
    const float* qkv_b = (const float*)d_in[4];
    const float* out_w = (const float*)d_in[5];
    const float* out_b = (const float*)d_in[6];
    float* y = (float*)d_out;
    char* ws = (char*)d_ws;

    float* a_arr  = (float*)(ws);
    float* bb_arr = (float*)(ws + 4096);
    unsigned short* wq     = (unsigned short*)(ws + 8192);      // 384KB
    unsigned short* w2     = (unsigned short*)(ws + 401408);    // 128KB
    unsigned short* q_seq  = (unsigned short*)(ws + 532480);    // 8MB
    unsigned short* k_seq  = (unsigned short*)(ws + 532480 + 8388608);
    unsigned short* vT     = (unsigned short*)(ws + 532480 + 2 * 8388608);
    unsigned short* o_part = (unsigned short*)(ws + 532480 + 3 * 8388608);  // 16MB
    float* m_part = (float*)(ws + 42475520);
    float* l_part = (float*)(ws + 42606592);

    (void)hipFuncSetAttribute((const void*)attn_kernel,
                              hipFuncAttributeMaxDynamicSharedMemorySize, 133120);

    prep_kernel<<<896, 256, 0, stream>>>(x, gn_w, gn_b, qkv_w, out_w,
                                         a_arr, bb_arr, wq, w2);
    qkv_gemm_kernel<<<dim3(64, 3, 4), 256, 0, stream>>>(x, a_arr, bb_arr, wq, qkv_b,
                                                        q_seq, k_seq, vT);
    attn_kernel<<<256, 512, 133120, stream>>>(q_seq, k_seq, vT, o_part, m_part, l_part);
    combine_kernel<<<512, 256, 0, stream>>>(o_part, m_part, l_part, w2, out_b, x, y);
}